// Round 10
// baseline (446.340 us; speedup 1.0000x reference)
//
#include <hip/hip_runtime.h>
#include <math.h>

#define B_ 64
#define N_ 2048
#define O_ 32
#define I_ 16
#define D_ 32
#define OD_ 1024

typedef __attribute__((ext_vector_type(8))) short bf16x8;
typedef __attribute__((ext_vector_type(4))) float f32x4;

union FragU { unsigned u[4]; uint4 v; bf16x8 f; };

// lgkm-only barrier: does not drain vmcnt.
__device__ __forceinline__ void barrier_lds() {
  asm volatile("s_waitcnt lgkmcnt(0)\n\ts_barrier" ::: "memory");
}

// ---- DPP cross-lane (VALU pipe) ----
template <int CTRL>
__device__ __forceinline__ float dpp_mov_f(float x) {
  return __int_as_float(
      __builtin_amdgcn_update_dpp(0, __float_as_int(x), CTRL, 0xf, 0xf, true));
}
__device__ __forceinline__ float row16_sum(float x) {
  x += dpp_mov_f<0x128>(x);
  x += dpp_mov_f<0x124>(x);
  x += dpp_mov_f<0x4e>(x);
  x += dpp_mov_f<0xb1>(x);
  return x;
}
__device__ __forceinline__ float grp32_max(float x) {
  x = fmaxf(x, dpp_mov_f<0xb1>(x));
  x = fmaxf(x, dpp_mov_f<0x4e>(x));
  x = fmaxf(x, dpp_mov_f<0x124>(x));
  x = fmaxf(x, dpp_mov_f<0x128>(x));
  x = fmaxf(x, __shfl_xor(x, 16));
  return x;
}
__device__ __forceinline__ float grp32_sum(float x) {
  x += dpp_mov_f<0xb1>(x);
  x += dpp_mov_f<0x4e>(x);
  x += dpp_mov_f<0x124>(x);
  x += dpp_mov_f<0x128>(x);
  x += __shfl_xor(x, 16);
  return x;
}

__device__ __forceinline__ void dk_split(float f, unsigned &h, unsigned &l) {
  unsigned u = __float_as_uint(f);
  h = u & 0xffff0000u;
  float lo = f - __uint_as_float(h);
  l = __float_as_uint(lo) >> 16;
}
__device__ __forceinline__ void dk_split16(float f, unsigned short &h,
                                           unsigned short &l) {
  unsigned u = __float_as_uint(f);
  unsigned hu = u & 0xffff0000u;
  h = (unsigned short)(u >> 16);
  float lo = f - __uint_as_float(hu);
  l = (unsigned short)(__float_as_uint(lo) >> 16);
}
__device__ __forceinline__ unsigned pk(unsigned short e0, unsigned short e1) {
  return (unsigned)e0 | ((unsigned)e1 << 16);
}

// ---- prep_x: x[b][n][i] fp32 -> XP packed A-fragments ----
// XP u4 idx = bg*131072 + n*64 + sel*32 + qp*16 + c ; b = bg*16 + c
__global__ __launch_bounds__(256) void prep_x(const float* __restrict__ x,
                                              uint4* __restrict__ XP) {
  int t = blockIdx.x * 256 + threadIdx.x;  // 131,072
  int c = t & 15, n = (t >> 4) & 2047, bg = t >> 15;
  const float* xp = x + ((size_t)(bg * 16 + c) * N_ + n) * I_;
  unsigned short hh[I_], ll[I_];
#pragma unroll
  for (int i = 0; i < I_; ++i) dk_split16(xp[i], hh[i], ll[i]);
  size_t base = ((size_t)bg * N_ + n) * 4;
#pragma unroll
  for (int sel = 0; sel < 2; ++sel) {
    const unsigned short* e = sel ? ll : hh;
#pragma unroll
    for (int qp = 0; qp < 2; ++qp) {
      uint4 u;
      u.x = pk(e[qp * 8 + 0], e[qp * 8 + 1]);
      u.y = pk(e[qp * 8 + 2], e[qp * 8 + 3]);
      u.z = pk(e[qp * 8 + 4], e[qp * 8 + 5]);
      u.w = pk(e[qp * 8 + 6], e[qp * 8 + 7]);
      XP[(base + sel * 2 + qp) * 16 + c] = u;
    }
  }
}

// ---- prep_w standalone (tier-2 fallback) ----
__global__ __launch_bounds__(256) void prep_w(const float* __restrict__ W,
                                              uint4* __restrict__ WP) {
  int t = blockIdx.x * 256 + threadIdx.x;  // 2,097,152 = n*o*d
  int d = t & 31, o = (t >> 5) & 31, n = t >> 10;
  const float* wp = W + ((size_t)(n * O_ + o) * I_) * D_ + d;
  unsigned short hh[I_], ll[I_];
#pragma unroll
  for (int i = 0; i < I_; ++i) dk_split16(wp[i * D_], hh[i], ll[i]);
  int c = d & 15, dhalf = d >> 4;
  size_t base = ((size_t)(n * O_ + o) * 2 + dhalf) * 4;
#pragma unroll
  for (int sel = 0; sel < 2; ++sel) {
    const unsigned short* e = sel ? ll : hh;
#pragma unroll
    for (int qp = 0; qp < 2; ++qp) {
      uint4 u;
      u.x = pk(e[qp * 8 + 0], e[qp * 8 + 1]);
      u.y = pk(e[qp * 8 + 2], e[qp * 8 + 3]);
      u.z = pk(e[qp * 8 + 4], e[qp * 8 + 5]);
      u.w = pk(e[qp * 8 + 6], e[qp * 8 + 7]);
      WP[(base + sel * 2 + qp) * 16 + c] = u;
    }
  }
}

// ---- fused: W split/pack -> WP  AND  uniform pass-1 s-accumulation ----
// 256 blocks x 1024 thr; block = chunk of NC=8 n, ALL 64 b, all 1024 od.
// Wave w owns o = 2w,2w+1 (4 tiles). Lane (q,c) loads raw W rows i=qp*8..+8
// at d=dh*16+c, splits; q<2 keeps hi, q>=2 keeps lo == exactly the [wh|wl]
// B-fragment record rec=q. Store to WP + MFMA vs 4 staged XP b-groups.
__global__ __launch_bounds__(1024, 4) void fused_w1(
    const float* __restrict__ W, const uint4* __restrict__ XP,
    uint4* __restrict__ WP, float* __restrict__ partial, int NC) {
  const int tid = threadIdx.x;
  const int lane = tid & 63;
  const int w = tid >> 6;
  const int q = lane >> 4;
  const int c = lane & 15;
  const int qp = q & 1;
  const int ch = blockIdx.x;
  const int n0 = ch * NC;

  __shared__ uint4 xps2[4][8][4][16];  // [bg][nl][rec][c] = 32 KB

  // stage XP for all 4 b-groups of this chunk
  {
    uint4* xf = (uint4*)xps2;
    const int total = 4 * 8 * 64;  // 2048
    for (int l = tid; l < total; l += 1024) {
      int bg = l >> 9;           // / 512
      int rest = l & 511;        // nl*64 + rec*16 + c
      xf[l] = XP[(size_t)bg * 131072 + (size_t)n0 * 64 + rest];
    }
  }

  f32x4 s_t[4][4];
#pragma unroll
  for (int bg = 0; bg < 4; ++bg)
#pragma unroll
    for (int ct = 0; ct < 4; ++ct) s_t[bg][ct] = (f32x4){0.f, 0.f, 0.f, 0.f};

  __syncthreads();

  for (int nl = 0; nl < NC; ++nl) {
    const size_t n = (size_t)(n0 + nl);
#pragma unroll
    for (int ct = 0; ct < 4; ++ct) {
      const int ol = ct >> 1, dh = ct & 1;
      const int o = 2 * w + ol;
      // raw W: rows i = qp*8 .. qp*8+7 at column d = dh*16 + c
      const float* wpp = W + (((size_t)n * O_ + o) * I_ + qp * 8) * D_ + dh * 16 + c;
      float w8[8];
#pragma unroll
      for (int j = 0; j < 8; ++j) w8[j] = wpp[j * D_];
      FragU b1, b2;
#pragma unroll
      for (int p = 0; p < 4; ++p) {
        unsigned short h0, l0, h1, l1;
        dk_split16(w8[2 * p], h0, l0);
        dk_split16(w8[2 * p + 1], h1, l1);
        b1.u[p] = pk(h0, h1);
        b2.u[p] = pk(l0, l1);
      }
      FragU cb;
      cb.v = (q < 2) ? b1.v : b2.v;  // rec q<2 = hi, q>=2 = lo
      WP[n * 4096 + o * 128 + dh * 64 + lane] = cb.v;
      // uniform MFMA vs all 4 b-groups
#pragma unroll
      for (int bg = 0; bg < 4; ++bg) {
        FragU ah, al;
        ah.v = xps2[bg][nl][qp][c];      // [xh|xh]
        al.v = xps2[bg][nl][2 + qp][c];  // [xl|xl]
        s_t[bg][ct] = __builtin_amdgcn_mfma_f32_16x16x32_bf16(
            ah.f, cb.f, s_t[bg][ct], 0, 0, 0);
        s_t[bg][ct] = __builtin_amdgcn_mfma_f32_16x16x32_bf16(
            al.f, cb.f, s_t[bg][ct], 0, 0, 0);
      }
    }
  }

#pragma unroll
  for (int bg = 0; bg < 4; ++bg)
#pragma unroll
    for (int ct = 0; ct < 4; ++ct) {
      int odc = (2 * w + (ct >> 1)) * 32 + (ct & 1) * 16 + c;
#pragma unroll
      for (int r = 0; r < 4; ++r) {
        partial[((size_t)ch * B_ + bg * 16 + q * 4 + r) * OD_ + odc] =
            s_t[bg][ct][r] * (1.f / 32.f);
      }
    }
}

// ---- fused routing pass v6 (unchanged from R9): 32-b block, XP in LDS ----
template <int UNIFORM>
__global__ __launch_bounds__(1024, 4) void mfma_pass6(
    const uint4* __restrict__ XP, const uint4* __restrict__ WP,
    const float* __restrict__ v, float* __restrict__ partial, int NC) {
  const int tid = threadIdx.x;
  const int lane = tid & 63;
  const int w = tid >> 6;
  const int q = lane >> 4;
  const int c = lane & 15;
  const int qp = q & 1;
  const int ch = blockIdx.x;
  const int bgy = blockIdx.y;

  __shared__ uint4 xps[2][16][4][16];  // 32 KB
  __shared__ float ls_logit[32 * O_];
  __shared__ float ls_c[32 * O_];

  const int n0 = ch * NC;

  {
    uint4* xf = (uint4*)xps;
    const int total = 2 * NC * 64;
    for (int l = tid; l < total; l += 1024) {
      int bgl = l / (NC * 64);
      int rest = l - bgl * (NC * 64);
      xf[bgl * 1024 + rest] =
          XP[(size_t)(bgy * 2 + bgl) * 131072 + (size_t)n0 * 64 + rest];
    }
  }

  f32x4 s_t[2][4];
#pragma unroll
  for (int bgl = 0; bgl < 2; ++bgl)
#pragma unroll
    for (int ct = 0; ct < 4; ++ct) s_t[bgl][ct] = (f32x4){0.f, 0.f, 0.f, 0.f};

  float vreg[2][4][4];
  if (!UNIFORM) {
#pragma unroll
    for (int bgl = 0; bgl < 2; ++bgl)
#pragma unroll
      for (int ct = 0; ct < 4; ++ct) {
        int odc = (2 * w + (ct >> 1)) * 32 + (ct & 1) * 16 + c;
#pragma unroll
        for (int r = 0; r < 4; ++r)
          vreg[bgl][ct][r] =
              v[(size_t)(bgy * 32 + bgl * 16 + q * 4 + r) * OD_ + odc];
      }
  }

  barrier_lds();

  const uint4* wbase = WP + (size_t)(2 * w) * 128 + lane;

  for (int nl = 0; nl < NC; ++nl) {
    const size_t n = (size_t)(n0 + nl);

    FragU cb[4];
#pragma unroll
    for (int ct = 0; ct < 4; ++ct) cb[ct].v = wbase[n * 4096 + ct * 64];

    if (UNIFORM) {
#pragma unroll
      for (int bgl = 0; bgl < 2; ++bgl) {
        FragU ah, al;
        ah.v = xps[bgl][nl][qp][c];
        al.v = xps[bgl][nl][2 + qp][c];
#pragma unroll
        for (int ct = 0; ct < 4; ++ct) {
          s_t[bgl][ct] = __builtin_amdgcn_mfma_f32_16x16x32_bf16(
              ah.f, cb[ct].f, s_t[bgl][ct], 0, 0, 0);
          s_t[bgl][ct] = __builtin_amdgcn_mfma_f32_16x16x32_bf16(
              al.f, cb[ct].f, s_t[bgl][ct], 0, 0, 0);
        }
      }
    } else {
      float lg[2][2][4];
#pragma unroll
      for (int bgl = 0; bgl < 2; ++bgl)
#pragma unroll
        for (int ol = 0; ol < 2; ++ol)
#pragma unroll
          for (int r = 0; r < 4; ++r) lg[bgl][ol][r] = 0.f;
#pragma unroll
      for (int bgl = 0; bgl < 2; ++bgl) {
        FragU ah, al;
        ah.v = xps[bgl][nl][qp][c];
        al.v = xps[bgl][nl][2 + qp][c];
#pragma unroll
        for (int ct = 0; ct < 4; ++ct) {
          f32x4 acc = (f32x4){0.f, 0.f, 0.f, 0.f};
          acc = __builtin_amdgcn_mfma_f32_16x16x32_bf16(ah.f, cb[ct].f, acc, 0, 0, 0);
          f32x4 u = __builtin_amdgcn_mfma_f32_16x16x32_bf16(al.f, cb[ct].f, acc, 0, 0, 0);
          int ol = ct >> 1;
#pragma unroll
          for (int r = 0; r < 4; ++r)
            lg[bgl][ol][r] = fmaf(u[r], vreg[bgl][ct][r], lg[bgl][ol][r]);
        }
      }
#pragma unroll
      for (int bgl = 0; bgl < 2; ++bgl)
#pragma unroll
        for (int ol = 0; ol < 2; ++ol)
#pragma unroll
          for (int r = 0; r < 4; ++r) lg[bgl][ol][r] = row16_sum(lg[bgl][ol][r]);
      if (c == 0) {
#pragma unroll
        for (int bgl = 0; bgl < 2; ++bgl)
#pragma unroll
          for (int ol = 0; ol < 2; ++ol)
#pragma unroll
            for (int r = 0; r < 4; ++r)
              ls_logit[(bgl * 16 + q * 4 + r) * O_ + 2 * w + ol] = lg[bgl][ol][r];
      }
      barrier_lds();
      {
        float l = ls_logit[tid];
        float mx = grp32_max(l);
        float e = __expf(l - mx);
        float sm = grp32_sum(e);
        ls_c[tid] = e / sm;
      }
      barrier_lds();
#pragma unroll
      for (int bgl = 0; bgl < 2; ++bgl) {
        FragU ah, al;
        ah.v = xps[bgl][nl][qp][c];
        al.v = xps[bgl][nl][2 + qp][c];
#pragma unroll
        for (int ct = 0; ct < 4; ++ct) {
          f32x4 acc = (f32x4){0.f, 0.f, 0.f, 0.f};
          acc = __builtin_amdgcn_mfma_f32_16x16x32_bf16(ah.f, cb[ct].f, acc, 0, 0, 0);
          f32x4 u = __builtin_amdgcn_mfma_f32_16x16x32_bf16(al.f, cb[ct].f, acc, 0, 0, 0);
          int o = 2 * w + (ct >> 1);
#pragma unroll
          for (int r = 0; r < 4; ++r) {
            float cc = ls_c[(bgl * 16 + q * 4 + r) * O_ + o];
            s_t[bgl][ct][r] = fmaf(cc, u[r], s_t[bgl][ct][r]);
          }
        }
      }
    }
  }

  const float scale = UNIFORM ? (1.f / 32.f) : 1.f;
#pragma unroll
  for (int bgl = 0; bgl < 2; ++bgl)
#pragma unroll
    for (int ct = 0; ct < 4; ++ct) {
      int odc = (2 * w + (ct >> 1)) * 32 + (ct & 1) * 16 + c;
#pragma unroll
      for (int r = 0; r < 4; ++r) {
        partial[((size_t)ch * B_ + bgy * 32 + bgl * 16 + q * 4 + r) * OD_ + odc] =
            s_t[bgl][ct][r] * scale;
      }
    }
}

// ---- fallback (round-2 path) ----
template <int UNIFORM>
__global__ __launch_bounds__(512, 4) void mfma_pass_fb(
    const float* __restrict__ x, const float* __restrict__ W,
    const float* __restrict__ v, float* __restrict__ partial, int NC) {
  const int tid = threadIdx.x;
  const int lane = tid & 63;
  const int cg = tid >> 6;
  const int q = lane >> 4;
  const int c = lane & 15;
  const int ch = blockIdx.x;
  const int bg = blockIdx.y;

  __shared__ float ls_logit[16 * O_];
  __shared__ float ls_c[16 * O_];

  f32x4 s_t[8];
#pragma unroll
  for (int ct = 0; ct < 8; ++ct) s_t[ct] = (f32x4){0.f, 0.f, 0.f, 0.f};

  const int n0 = ch * NC;
  const int ih = (q & 1) * 8;
  const float* xrow = x + ((size_t)(bg * 16 + c) * N_) * I_ + ih;

  for (int nl = 0; nl < NC; ++nl) {
    const int n = n0 + nl;
    const float* xp = xrow + (size_t)n * I_;
    float4 xv0 = *(const float4*)xp;
    float4 xv1 = *(const float4*)(xp + 4);
    float xv[8] = {xv0.x, xv0.y, xv0.z, xv0.w, xv1.x, xv1.y, xv1.z, xv1.w};
    FragU a1;
#pragma unroll
    for (int p = 0; p < 4; ++p) {
      unsigned h0, l0, h1, l1;
      dk_split(xv[2 * p], h0, l0);
      dk_split(xv[2 * p + 1], h1, l1);
      a1.u[p] = (q < 2) ? ((h0 >> 16) | h1) : (l0 | (l1 << 16));
    }
    f32x4 u_t[8];
#pragma unroll
    for (int ct = 0; ct < 8; ++ct) {
      const int o = cg * 4 + (ct >> 1);
      const int d = (ct & 1) * 16 + c;
      const float* wp = W + (((size_t)n * O_ + o) * I_ + ih) * D_ + d;
      FragU b1, b2;
#pragma unroll
      for (int p = 0; p < 4; ++p) {
        unsigned h0, l0, h1, l1;
        dk_split(wp[(2 * p) * D_], h0, l0);
        dk_split(wp[(2 * p + 1) * D_], h1, l1);
        b1.u[p] = (h0 >> 16) | h1;
        b2.u[p] = l0 | (l1 << 16);
      }
      if (UNIFORM) {
        s_t[ct] = __builtin_amdgcn_mfma_f32_16x16x32_bf16(a1.f, b1.f, s_t[ct], 0, 0, 0);
        s_t[ct] = __builtin_amdgcn_mfma_f32_16x16x32_bf16(a1.f, b2.f, s_t[ct], 0, 0, 0);
      } else {
        f32x4 acc = (f32x4){0.f, 0.f, 0.f, 0.f};
        acc = __builtin_amdgcn_mfma_f32_16x16x32_bf16(a1.f, b1.f, acc, 0, 0, 0);
        u_t[ct] = __builtin_amdgcn_mfma_f32_16x16x32_bf16(a1.f, b2.f, acc, 0, 0, 0);
      }
    }
    if (!UNIFORM) {
#pragma unroll
      for (int ol = 0; ol < 4; ++ol) {
        float lg[4] = {0.f, 0.f, 0.f, 0.f};
#pragma unroll
        for (int hf = 0; hf < 2; ++hf) {
          int ct = ol * 2 + hf;
          int odc = cg * 128 + ct * 16 + c;
#pragma unroll
          for (int r = 0; r < 4; ++r)
            lg[r] = fmaf(u_t[ct][r], v[(size_t)(bg * 16 + q * 4 + r) * OD_ + odc], lg[r]);
        }
#pragma unroll
        for (int r = 0; r < 4; ++r) {
#pragma unroll
          for (int m = 1; m < 16; m <<= 1) lg[r] += __shfl_xor(lg[r], m);
        }
        if (c == 0) {
#pragma unroll
          for (int r = 0; r < 4; ++r)
            ls_logit[(q * 4 + r) * O_ + cg * 4 + ol] = lg[r];
        }
      }
      __syncthreads();
      {
        int b_l = tid >> 5, o = tid & 31;
        float l = ls_logit[b_l * O_ + o];
        float mx = l;
#pragma unroll
        for (int m = 16; m >= 1; m >>= 1) mx = fmaxf(mx, __shfl_xor(mx, m));
        float e = __expf(l - mx);
        float sm = e;
#pragma unroll
        for (int m = 16; m >= 1; m >>= 1) sm += __shfl_xor(sm, m);
        ls_c[b_l * O_ + o] = e / sm;
      }
      __syncthreads();
#pragma unroll
      for (int ol = 0; ol < 4; ++ol) {
        int o = cg * 4 + ol;
        float cc[4];
#pragma unroll
        for (int r = 0; r < 4; ++r) cc[r] = ls_c[(q * 4 + r) * O_ + o];
#pragma unroll
        for (int hf = 0; hf < 2; ++hf) {
          int ct = ol * 2 + hf;
#pragma unroll
          for (int r = 0; r < 4; ++r)
            s_t[ct][r] = fmaf(cc[r], u_t[ct][r], s_t[ct][r]);
        }
      }
    }
  }

  const float scale = UNIFORM ? (1.f / 32.f) : 1.f;
#pragma unroll
  for (int ct = 0; ct < 8; ++ct) {
#pragma unroll
    for (int r = 0; r < 4; ++r) {
      partial[((size_t)ch * B_ + bg * 16 + q * 4 + r) * OD_ + cg * 128 + ct * 16 + c] =
          s_t[ct][r] * scale;
    }
  }
}

// ---- two-stage reduce ----
__global__ __launch_bounds__(256) void reduce_stageA(float4* __restrict__ part,
                                                     int cq) {
  int qa = blockIdx.x >> 6;
  int g4 = (blockIdx.x & 63) * 256 + threadIdx.x;
  float4 s = make_float4(0.f, 0.f, 0.f, 0.f);
  for (int i = 0; i < cq; ++i) {
    float4 p = part[(size_t)(qa * cq + i) * 16384 + g4];
    s.x += p.x; s.y += p.y; s.z += p.z; s.w += p.w;
  }
  part[(size_t)(qa * cq) * 16384 + g4] = s;
}

__global__ __launch_bounds__(256) void reduce_stageB(
    const float4* __restrict__ part, int cq, const float4* __restrict__ prev,
    float4* __restrict__ out) {
  int g4 = blockIdx.x * 256 + threadIdx.x;
  float4 s = make_float4(0.f, 0.f, 0.f, 0.f);
#pragma unroll
  for (int qa = 0; qa < 4; ++qa) {
    float4 p = part[(size_t)(qa * cq) * 16384 + g4];
    s.x += p.x; s.y += p.y; s.z += p.z; s.w += p.w;
  }
  float sq = s.x * s.x + s.y * s.y + s.z * s.z + s.w * s.w;
#pragma unroll
  for (int m = 4; m >= 1; m >>= 1) sq += __shfl_xor(sq, m, 8);
  float scale = sq / ((1.f + sq) * (sqrtf(sq) + 1e-6f));
  float4 r = make_float4(s.x * scale, s.y * scale, s.z * scale, s.w * scale);
  if (prev) {
    float4 p = prev[g4];
    r.x += p.x; r.y += p.y; r.z += p.z; r.w += p.w;
  }
  out[g4] = r;
}

__global__ __launch_bounds__(256) void reduce_squash(
    const float4* __restrict__ part, int chunks,
    const float4* __restrict__ prev, float4* __restrict__ out) {
  int g4 = blockIdx.x * 256 + threadIdx.x;
  float4 s = make_float4(0.f, 0.f, 0.f, 0.f);
#pragma unroll 4
  for (int ch = 0; ch < chunks; ++ch) {
    float4 p = part[(size_t)ch * 16384 + g4];
    s.x += p.x; s.y += p.y; s.z += p.z; s.w += p.w;
  }
  float sq = s.x * s.x + s.y * s.y + s.z * s.z + s.w * s.w;
#pragma unroll
  for (int m = 4; m >= 1; m >>= 1) sq += __shfl_xor(sq, m, 8);
  float scale = sq / ((1.f + sq) * (sqrtf(sq) + 1e-6f));
  float4 r = make_float4(s.x * scale, s.y * scale, s.z * scale, s.w * scale);
  if (prev) {
    float4 p = prev[g4];
    r.x += p.x; r.y += p.y; r.z += p.z; r.w += p.w;
  }
  out[g4] = r;
}

extern "C" void kernel_launch(void* const* d_in, const int* in_sizes, int n_in,
                              void* d_out, int out_size, void* d_ws,
                              size_t ws_size, hipStream_t stream) {
  const float* x = (const float*)d_in[0];
  const float* W = (const float*)d_in[1];
  float* out = (float*)d_out;

  const size_t XP_FLOATS = 4ull * 2048 * 4 * 16 * 4;       // 2,097,152
  const size_t WP_FLOATS = 2048ull * 32 * 2 * 4 * 16 * 4;  // 33,554,432

  float* v1 = (float*)d_ws;
  float* vsum = v1 + 65536;
  float* partial = vsum + 65536;

  const size_t need256 =
      (131072 + 256ull * 65536 + XP_FLOATS + WP_FLOATS) * 4;  // ~210 MB
  const size_t need128 =
      (131072 + 128ull * 65536 + XP_FLOATS + WP_FLOATS) * 4;  // ~176 MB

  if (ws_size >= need256) {
    // tier 1: fused prep_w + pass1 (256 chunks, NC=8); routing at 128 chunks
    uint4* XP = (uint4*)(partial + 256ull * 65536);
    uint4* WP = XP + XP_FLOATS / 4;

    prep_x<<<512, 256, 0, stream>>>(x, XP);
    fused_w1<<<256, 1024, 0, stream>>>(W, XP, WP, partial, 8);
    reduce_stageA<<<256, 256, 0, stream>>>((float4*)partial, 64);
    reduce_stageB<<<64, 256, 0, stream>>>((const float4*)partial, 64, nullptr,
                                          (float4*)v1);
    dim3 grid(128, 2);
    mfma_pass6<0><<<grid, 1024, 0, stream>>>(XP, WP, v1, partial, 16);
    reduce_stageA<<<256, 256, 0, stream>>>((float4*)partial, 32);
    reduce_stageB<<<64, 256, 0, stream>>>((const float4*)partial, 32,
                                          (const float4*)v1, (float4*)vsum);
    mfma_pass6<0><<<grid, 1024, 0, stream>>>(XP, WP, vsum, partial, 16);
    reduce_stageA<<<256, 256, 0, stream>>>((float4*)partial, 32);
    reduce_stageB<<<64, 256, 0, stream>>>((const float4*)partial, 32, nullptr,
                                          (float4*)out);
  } else if (ws_size >= need128) {
    // tier 2: R9 structure
    uint4* XP = (uint4*)(partial + 128ull * 65536);
    uint4* WP = XP + XP_FLOATS / 4;
    dim3 grid(128, 2);

    prep_x<<<512, 256, 0, stream>>>(x, XP);
    prep_w<<<8192, 256, 0, stream>>>(W, WP);

    mfma_pass6<1><<<grid, 1024, 0, stream>>>(XP, WP, nullptr, partial, 16);
    reduce_stageA<<<256, 256, 0, stream>>>((float4*)partial, 32);
    reduce_stageB<<<64, 256, 0, stream>>>((const float4*)partial, 32, nullptr,
                                          (float4*)v1);
    mfma_pass6<0><<<grid, 1024, 0, stream>>>(XP, WP, v1, partial, 16);
    reduce_stageA<<<256, 256, 0, stream>>>((float4*)partial, 32);
    reduce_stageB<<<64, 256, 0, stream>>>((const float4*)partial, 32,
                                          (const float4*)v1, (float4*)vsum);
    mfma_pass6<0><<<grid, 1024, 0, stream>>>(XP, WP, vsum, partial, 16);
    reduce_stageA<<<256, 256, 0, stream>>>((float4*)partial, 32);
    reduce_stageB<<<64, 256, 0, stream>>>((const float4*)partial, 32, nullptr,
                                          (float4*)out);
  } else {
    // tier 3: no-workspace-packing fallback
    int fchunks = 128;
    while (fchunks > 1 && (131072 + (size_t)fchunks * 65536) * 4 > ws_size)
      fchunks >>= 1;
    int NC = N_ / fchunks;
    dim3 grid(fchunks, 4);

    mfma_pass_fb<1><<<grid, 512, 0, stream>>>(x, W, nullptr, partial, NC);
    reduce_squash<<<64, 256, 0, stream>>>((const float4*)partial, fchunks,
                                          nullptr, (float4*)v1);
    mfma_pass_fb<0><<<grid, 512, 0, stream>>>(x, W, v1, partial, NC);
    reduce_squash<<<64, 256, 0, stream>>>((const float4*)partial, fchunks,
                                          (const float4*)v1, (float4*)vsum);
    mfma_pass_fb<0><<<grid, 512, 0, stream>>>(x, W, vsum, partial, NC);
    reduce_squash<<<64, 256, 0, stream>>>((const float4*)partial, fchunks,
                                          nullptr, (float4*)out);
  }
}